// Round 11
// baseline (246.741 us; speedup 1.0000x reference)
//
#include <hip/hip_runtime.h>
#include <hip/hip_bf16.h>
#include <stdint.h>

typedef unsigned short u16;
typedef __attribute__((ext_vector_type(8))) short short8;
typedef __attribute__((ext_vector_type(4))) short short4v;
typedef __attribute__((ext_vector_type(4))) float f32x4;

#define MFMA16(a,b,c) __builtin_amdgcn_mfma_f32_16x16x32_bf16((a),(b),(c),0,0,0)
#define EXP2F(x) __builtin_amdgcn_exp2f(x)

typedef const __attribute__((address_space(1))) void glb_void;
typedef __attribute__((address_space(3))) void lds_void;

__device__ __forceinline__ u16 f2b(float f){
  unsigned u = __float_as_uint(f);
  u += 0x7fffu + ((u>>16)&1u);
  return (u16)(u>>16);
}
__device__ __forceinline__ unsigned pack_bf16(float a, float b){
  __hip_bfloat162 h = __float22bfloat162_rn(make_float2(a,b));
  unsigned u; __builtin_memcpy(&u, &h, 4); return u;
}
__device__ __forceinline__ void gld16(const void* g, void* l){
  __builtin_amdgcn_global_load_lds((glb_void*)g, (lds_void*)l, 16, 0, 0);
}

// ---- swizzled layout: LDS[row][c] = G[row][ (c/8 ^ (row&7))*8 + c%8 ] ----
__device__ __forceinline__ const short8* frag64(const u16* lds, int row, int c16){
  return (const short8*)(lds + row*64 + ((c16 ^ (row&7))<<3));
}
__device__ __forceinline__ const short8* frag128(const u16* lds, int row, int c16){
  return (const short8*)(lds + row*128 + ((c16 ^ (row&15))<<3));
}

// ================= PREP: weight cvt + mask classes + q/k/v transposes, one dispatch =======
// mask classes: 0 = all-zero, 2 = all-masked, 3 = EXACT causal, 1 = other (fallback load).
__global__ __launch_bounds__(256) void prep(
    const float* __restrict__ q, const float* __restrict__ k, const float* __restrict__ v,
    const float* __restrict__ qkm, const float* __restrict__ km,
    const float* __restrict__ Wq, const float* __restrict__ Wk,
    const float* __restrict__ Wv, const float* __restrict__ Wo,
    u16* __restrict__ W16, char* __restrict__ classes,
    u16* __restrict__ qT, u16* __restrict__ kT, u16* __restrict__ vT)
{
  __shared__ __align__(16) float t[64][72];
  const int bx = blockIdx.x, tid = threadIdx.x;
  const int S = 2048, E = 1024, nW = E*E;
  const float NEG = -1e4f;

  if (bx < 2048){                      // ---- weight convert ----
    const int sel = bx>>9, blk = bx&511;
    const float* src = sel==0?Wq : sel==1?Wk : sel==2?Wv : Wo;
    const float sc = (sel==0) ? 0.18033688f : 1.0f;   // 0.125 * log2(e)
    u16* dst = W16 + (size_t)sel*nW;
    int i = (blk*256 + tid)*8;
    float4 a = *(const float4*)(src+i);
    float4 b = *(const float4*)(src+i+4);
    short8 o;
    o[0]=(short)f2b(a.x*sc); o[1]=(short)f2b(a.y*sc); o[2]=(short)f2b(a.z*sc); o[3]=(short)f2b(a.w*sc);
    o[4]=(short)f2b(b.x*sc); o[5]=(short)f2b(b.y*sc); o[6]=(short)f2b(b.z*sc); o[7]=(short)f2b(b.w*sc);
    *(short8*)(dst+i) = o;
  } else if (bx < 4096){               // ---- mask tile classification (64x64) ----
    const int tt = bx - 2048;
    const int b = tt>>10, qi = (tt>>5)&31, ki = tt&31;
    const int k0 = ki*64, q0 = qi*64;
    int az = 1, an = 1, ac = 1;
    #pragma unroll
    for (int p=0;p<4;++p){
      int e = tid + p*256;
      int row = e>>4, c4 = (e&15)*4;
      const int kg = k0 + row;
      float kmv = km[(size_t)b*S + kg];
      float4 mv = *(const float4*)&qkm[((size_t)b*S + kg)*S + q0 + c4];
      mv.x += kmv; mv.y += kmv; mv.z += kmv; mv.w += kmv;
      az &= (mv.x==0.f) & (mv.y==0.f) & (mv.z==0.f) & (mv.w==0.f);
      an &= (mv.x<-1e3f) & (mv.y<-1e3f) & (mv.z<-1e3f) & (mv.w<-1e3f);
      const float e0 = (kg > q0+c4+0) ? NEG : 0.f;
      const float e1 = (kg > q0+c4+1) ? NEG : 0.f;
      const float e2 = (kg > q0+c4+2) ? NEG : 0.f;
      const float e3 = (kg > q0+c4+3) ? NEG : 0.f;
      ac &= (mv.x==e0) & (mv.y==e1) & (mv.z==e2) & (mv.w==e3);
    }
    const int az_all = __syncthreads_and(az);
    const int an_all = __syncthreads_and(an);
    const int ac_all = __syncthreads_and(ac);
    if (tid==0)
      classes[((size_t)b*32 + qi)*32 + ki] =
          an_all ? 2 : (az_all ? 0 : (ac_all ? 3 : 1));
  } else {                             // ---- transpose+convert q/k/v ----
    const int tt = bx - 4096;
    const int tensor = tt>>10, r = tt&1023;
    const int b = r>>9, rr = r&511;
    const int c0 = (rr>>5)*64, s0 = (rr&31)*64;
    const float* x = tensor==0 ? q : tensor==1 ? k : v;
    u16* xt = tensor==0 ? qT : tensor==1 ? kT : vT;
    #pragma unroll
    for (int p=0;p<4;++p){
      int e = tid + p*256;
      int row = e>>4, c4 = (e&15)*4;
      *(float4*)&t[row][c4] = *(const float4*)&x[((size_t)b*E + c0 + row)*S + s0 + c4];
    }
    __syncthreads();
    #pragma unroll
    for (int p=0;p<2;++p){
      int e = tid + p*256;
      int row = e>>3, col8 = (e&7)*8;
      short8 o;
      #pragma unroll
      for (int u=0;u<8;++u) o[u] = (short)f2b(t[col8+u][row]);
      *(short8*)&xt[((size_t)b*S + s0 + row)*E + c0 + col8] = o;
    }
  }
}

// ---------------- GEMM core: C[M][N] = A[M][K]*Bt[N][K]^T + bias*bscale -------------------
template<bool F32OUT>
__device__ __forceinline__ void gemm_core(
    const u16* __restrict__ A, const u16* __restrict__ Bt, const float* __restrict__ bias,
    float bscale, void* __restrict__ Cv, size_t cbase, int N, int K, int bias_on_m,
    int m0, int n0, u16* As, u16* Bs)
{
  const int tid = threadIdx.x, w = tid>>6, lane = tid&63;
  const int ln = lane&15, quad = lane>>4;
  const int m0w = (w>>1)*64, n0w = (w&1)*64;
  const int sub = lane>>3, gcol = ((lane&7)^sub)<<3;
  f32x4 acc[4][4];
  #pragma unroll
  for(int i=0;i<4;++i)
    #pragma unroll
    for(int j=0;j<4;++j) acc[i][j] = f32x4{0.f,0.f,0.f,0.f};

  short8 areg[4], breg[4];
  auto issue = [&](int kc){
    #pragma unroll
    for (int i=0;i<4;++i){
      const int r0 = (w*4+i)*8 + sub;
      areg[i] = *(const short8*)(A  + (size_t)(m0 + r0)*K + kc + gcol);
      breg[i] = *(const short8*)(Bt + (size_t)(n0 + r0)*K + kc + gcol);
    }
  };
  auto write_lds = [&](){
    #pragma unroll
    for (int i=0;i<4;++i){
      *(short8*)&As[(w*4+i)*512 + lane*8] = areg[i];
      *(short8*)&Bs[(w*4+i)*512 + lane*8] = breg[i];
    }
  };

  issue(0);
  for (int kc=0; kc<K; kc+=64){
    __builtin_amdgcn_s_barrier();                  // all waves done reading prev tile
    __builtin_amdgcn_sched_barrier(0);
    write_lds();                                   // implicit vmcnt wait on areg/breg
    if (kc+64 < K) issue(kc+64);                   // overlap next loads with compute
    asm volatile("s_waitcnt lgkmcnt(0)" ::: "memory");
    __builtin_amdgcn_s_barrier();
    __builtin_amdgcn_sched_barrier(0);
    #pragma unroll
    for (int kk=0; kk<64; kk+=32){
      const int c16 = (kk>>3) + quad;
      short8 af[4], bf[4];
      #pragma unroll
      for (int mt=0;mt<4;++mt) af[mt] = *frag64(As, m0w+mt*16+ln, c16);
      #pragma unroll
      for (int nt=0;nt<4;++nt) bf[nt] = *frag64(Bs, n0w+nt*16+ln, c16);
      #pragma unroll
      for (int mt=0;mt<4;++mt)
        #pragma unroll
        for (int nt=0;nt<4;++nt)
          acc[mt][nt] = MFMA16(af[mt], bf[nt], acc[mt][nt]);
    }
  }
  #pragma unroll
  for (int mt=0;mt<4;++mt){
    #pragma unroll
    for (int nt=0;nt<4;++nt){
      const int col = n0 + n0w + nt*16 + ln;
      const float bn = bias_on_m ? 0.f : bias[col]*bscale;
      #pragma unroll
      for (int r=0;r<4;++r){
        const int row = m0 + m0w + mt*16 + quad*4 + r;
        const float bb = bias_on_m ? bias[row]*bscale : bn;
        const float val = acc[mt][nt][r] + bb;
        const size_t idx = cbase + (size_t)row*N + col;
        if (F32OUT) ((float*)Cv)[idx] = val;
        else        ((u16*)Cv)[idx]   = f2b(val);
      }
    }
  }
}

// ================= PROJ: Q,K,V projections in one uniform dispatch (768 blocks) ===========
__global__ __launch_bounds__(256,2) void proj(
    const u16* __restrict__ qT, const u16* __restrict__ kT, const u16* __restrict__ vT,
    const u16* __restrict__ W16,
    const float* __restrict__ bq, const float* __restrict__ bk, const float* __restrict__ bv,
    u16* __restrict__ Qb, u16* __restrict__ Kb, u16* __restrict__ Vb)
{
  __shared__ __align__(16) u16 As[128*64];
  __shared__ __align__(16) u16 Bs[128*64];
  const int bx = blockIdx.x;
  const int zone = bx>>7, r = bx&127;
  const size_t sSE = (size_t)2048*1024;
  const int nW = 1024*1024;
  if (zone < 4){
    const int sel = zone>>1, b = zone&1;
    const int m0 = (r>>3)*128, n0 = (r&7)*128;
    gemm_core<false>((sel? kT : qT) + b*sSE, W16 + (size_t)sel*nW, sel? bk : bq,
                     sel? 1.0f : 0.18033688f, sel? Kb : Qb, b*sSE,
                     1024, 1024, 0, m0, n0, As, Bs);
  } else {
    const int b = zone&1;
    const int m0 = (r>>4)*128, n0 = (r&15)*128;
    gemm_core<false>(W16 + (size_t)2*nW, vT + b*sSE, bv,
                     1.0f, Vb, b*sSE,
                     2048, 1024, 1, m0, n0, As, Bs);
  }
}

// ================= OUT GEMM: 64x128 tiles, 512 blocks = 2/CU, reg-staged pipeline =========
__global__ __launch_bounds__(256,3) void gemm_out64(
    const u16* __restrict__ Wo16, const u16* __restrict__ At, const float* __restrict__ bo,
    float* __restrict__ out)
{
  __shared__ __align__(16) u16 As[64*64];
  __shared__ __align__(16) u16 Bs[128*64];
  const int b = blockIdx.z;
  const int m0 = blockIdx.y*64, n0 = blockIdx.x*128;
  const size_t sSE = (size_t)2048*1024;
  const int K = 1024, N = 2048;
  const u16* Bt = At + b*sSE;
  const int tid = threadIdx.x, w = tid>>6, lane = tid&63;
  const int ln = lane&15, quad = lane>>4;
  const int m0w = (w>>1)*32, n0w = (w&1)*64;
  const int sub = lane>>3, gcol = ((lane&7)^sub)<<3;
  f32x4 acc[2][4];
  #pragma unroll
  for(int i=0;i<2;++i)
    #pragma unroll
    for(int j=0;j<4;++j) acc[i][j] = f32x4{0.f,0.f,0.f,0.f};

  short8 areg[2], breg[4];
  auto issue = [&](int kc){
    #pragma unroll
    for (int i=0;i<2;++i){
      const int r0 = (w*2+i)*8 + sub;
      areg[i] = *(const short8*)(Wo16 + (size_t)(m0 + r0)*K + kc + gcol);
    }
    #pragma unroll
    for (int i=0;i<4;++i){
      const int r0 = (w*4+i)*8 + sub;
      breg[i] = *(const short8*)(Bt + (size_t)(n0 + r0)*K + kc + gcol);
    }
  };
  auto write_lds = [&](){
    #pragma unroll
    for (int i=0;i<2;++i)
      *(short8*)&As[(w*2+i)*512 + lane*8] = areg[i];
    #pragma unroll
    for (int i=0;i<4;++i)
      *(short8*)&Bs[(w*4+i)*512 + lane*8] = breg[i];
  };

  issue(0);
  for (int kc=0; kc<K; kc+=64){
    __builtin_amdgcn_s_barrier();
    __builtin_amdgcn_sched_barrier(0);
    write_lds();
    if (kc+64 < K) issue(kc+64);
    asm volatile("s_waitcnt lgkmcnt(0)" ::: "memory");
    __builtin_amdgcn_s_barrier();
    __builtin_amdgcn_sched_barrier(0);
    #pragma unroll
    for (int kk=0; kk<64; kk+=32){
      const int c16 = (kk>>3) + quad;
      short8 af[2], bf[4];
      #pragma unroll
      for (int mt=0;mt<2;++mt) af[mt] = *frag64(As, m0w+mt*16+ln, c16);
      #pragma unroll
      for (int nt=0;nt<4;++nt) bf[nt] = *frag64(Bs, n0w+nt*16+ln, c16);
      #pragma unroll
      for (int mt=0;mt<2;++mt)
        #pragma unroll
        for (int nt=0;nt<4;++nt)
          acc[mt][nt] = MFMA16(af[mt], bf[nt], acc[mt][nt]);
    }
  }
  #pragma unroll
  for (int mt=0;mt<2;++mt){
    #pragma unroll
    for (int nt=0;nt<4;++nt){
      const int col = n0 + n0w + nt*16 + ln;
      #pragma unroll
      for (int r=0;r<4;++r){
        const int row = m0 + m0w + mt*16 + quad*4 + r;
        out[b*sSE + (size_t)row*N + col] = acc[mt][nt][r] + bo[row];
      }
    }
  }
}

// ================= fused flash attention (R11: k-split QK phase, shared P^T) ==============
// Block = 64 q-rows, 4 waves, 1024 blocks. Per k-tile, two phases:
//  QK: wave w owns k-slice [w*32,w*32+32) x ALL 64 q (Q in regs, 8 frags). Each K-frag
//      ds_read feeds 4 MFMAs (4 q-groups) -> QK LDS reads drop 16 -> 4 per wave-tile.
//      P^T written to the SHARED Ps[64q][128k] (same byte addresses as R10's verified
//      per-wave layout -- only the writer changes). Masked k-halves (class 2) zero-fill
//      and skip MFMAs/exps entirely.
//  barrier (lgkmcnt0 + s_barrier)
//  PV: unchanged from R10 (waves split by q). rs recovered exactly from the bf16 pf reads.
//      PV c-steps whose 64-k half is class 2 are skipped (P there is zero).
__global__ __launch_bounds__(256,2) void attn(
    const u16* __restrict__ Qb, const u16* __restrict__ Kb, const u16* __restrict__ Vb,
    const float* __restrict__ qk_mask, const float* __restrict__ k_mask,
    const char* __restrict__ classes, u16* __restrict__ Ot)
{
  __shared__ __align__(16) u16 Ks[128*64];
  __shared__ __align__(16) u16 Vs[64*128];
  __shared__ __align__(16) u16 Ps[64*128];        // shared P^T [64 q][128 k], 16 KB
  const int bx = blockIdx.x;
  const int st = 31 - (bx>>5);           // q-subtile 0..31, heavy (high-st) first
  const int bh = bx & 31;
  const int b = bh & 1, h = bh >> 1;
  const int tid = threadIdx.x, w = tid>>6, lane = tid&63;
  const int ln = lane&15, quad = lane>>4;
  const int S = 2048;
  const float LOG2E = 1.44269504f, C2 = 16.0f;

  // Q for ALL four 16-row groups (QK B-operands; wave sees all 64 q)
  short8 qfg[4][2];
  #pragma unroll
  for (int g=0;g<4;++g)
    #pragma unroll
    for (int kkI=0;kkI<2;++kkI)
      qfg[g][kkI] = *(const short8*)&Qb[((size_t)b*S + st*64 + g*16 + ln)*1024
                                        + h*64 + kkI*32 + quad*8];

  const char* cl = classes + ((size_t)b*32 + st)*32;
  unsigned mMe=0;
  #pragma unroll
  for (int kt=0;kt<16;++kt)
    if (!((cl[2*kt]==2) & (cl[2*kt+1]==2))) mMe |= 1u<<kt;

  float rs = 0.f;
  f32x4 acc[4];
  #pragma unroll
  for (int ct=0;ct<4;++ct) acc[ct] = f32x4{0.f,0.f,0.f,0.f};

  const int rsw = (ln&7)<<4;                       // row-XOR swizzle (row&7 == ln&7 here)
  char* Pme = (char*)Ps + (w*16+ln)*256;           // PV read base: my q rows

  // ---- reg staging (LDS linear, source pre-swizzled), 4 waves --------------------------
  const u16* gK = Kb + ((size_t)b*S)*1024 + h*64;
  const u16* gV = Vb + ((size_t)b*1024 + h*64)*S;
  const int subK = lane>>3, cK = ((lane&7)^subK)<<3;
  const int subV = lane>>4, cV0 = lane&15;

  short8 kreg[4], vreg[4];
  auto issue = [&](int kt){
    const int k0 = kt*128;
    #pragma unroll
    for (int i=0;i<4;++i){
      const int r = (w*4+i)*8 + subK;
      kreg[i] = *(const short8*)(gK + (size_t)(k0 + r)*1024 + cK);
    }
    #pragma unroll
    for (int i=0;i<4;++i){
      const int row = (w*4+i)*4 + subV;
      vreg[i] = *(const short8*)(gV + (size_t)row*S + k0 + ((cV0 ^ (row&15))<<3));
    }
  };
  auto write_lds = [&](){
    #pragma unroll
    for (int i=0;i<4;++i)
      *(short8*)&Ks[(w*4+i)*512 + lane*8] = kreg[i];
    #pragma unroll
    for (int i=0;i<4;++i)
      *(short8*)&Vs[(w*4+i)*512 + lane*8] = vreg[i];
  };

  auto compute = [&](int kt){
    const char chA = cl[2*kt], chB = cl[2*kt+1];
    const char ch = (w>>1) ? chB : chA;            // my k-slice's 64-half class
    const int k0 = kt*128;
    // ---- QK phase: k-slice [w*32, w*32+32), all 64 q --------------------------------
    if (ch == 2){
      uint2 z; z.x = 0u; z.y = 0u;
      #pragma unroll
      for (int t=0;t<2;++t)
        #pragma unroll
        for (int g=0;g<4;++g)
          *(uint2*)((char*)Ps + (g*16+ln)*256 + ((w*64 + t*32 + quad*8) ^ rsw)) = z;
    } else {
      const bool nomask = (ch==0);
      const bool analytic = (ch==3);
      #pragma unroll
      for (int t=0;t<2;++t){
        const int krow = w*32 + t*16 + ln;
        const short8 af0 = *frag64(Ks, krow, quad);
        const short8 af1 = *frag64(Ks, krow, 4 + quad);
        #pragma unroll
        for (int g=0;g<4;++g){
          f32x4 s = f32x4{0.f,0.f,0.f,0.f};
          s = MFMA16(af0, qfg[g][0], s);
          s = MFMA16(af1, qfg[g][1], s);
          const int qgg = st*64 + g*16 + ln;
          float e[4];
          if (nomask){
            #pragma unroll
            for (int r=0;r<4;++r) e[r] = EXP2F(s[r] - C2);
          } else if (analytic){
            #pragma unroll
            for (int r=0;r<4;++r){
              const int kg = k0 + w*32 + t*16 + quad*4 + r;
              e[r] = (kg <= qgg) ? EXP2F(s[r] - C2) : 0.f;
            }
          } else {
            #pragma unroll
            for (int r=0;r<4;++r){
              const int kg = k0 + w*32 + t*16 + quad*4 + r;
              const float m = qk_mask[((size_t)b*S + kg)*S + qgg] + k_mask[(size_t)b*S + kg];
              e[r] = EXP2F(fmaf(m, LOG2E, s[r]) - C2);
            }
          }
          uint2 pp;
          pp.x = pack_bf16(e[0], e[1]);
          pp.y = pack_bf16(e[2], e[3]);
          *(uint2*)((char*)Ps + (g*16+ln)*256 + ((w*64 + t*32 + quad*8) ^ rsw)) = pp;
        }
      }
    }
    asm volatile("s_waitcnt lgkmcnt(0)" ::: "memory");   // my P writes done
    __builtin_amdgcn_s_barrier();                        // all waves' P visible
    __builtin_amdgcn_sched_barrier(0);
    // ---- PV phase: my 16 q rows, full k ----------------------------------------------
    #pragma unroll
    for (int c=0;c<4;++c){
      const char chc = (c>>1) ? chB : chA;
      if (chc == 2) continue;                      // that 64-k half is all zeros
      const short8 pf = *(const short8*)(Pme + ((c*64 + quad*16) ^ rsw));
      #pragma unroll
      for (int i=0;i<4;++i){
        unsigned u = ((const unsigned*)&pf)[i];
        __hip_bfloat162 h2; __builtin_memcpy(&h2, &u, 4);
        float2 f2 = __bfloat1622float2(h2);
        rs += f2.x + f2.y;
      }
      __builtin_amdgcn_s_setprio(1);
      #pragma unroll
      for (int ct=0;ct<4;++ct)
        acc[ct] = MFMA16(*frag128(Vs, ct*16+ln, c*4 + quad), pf, acc[ct]);
      __builtin_amdgcn_s_setprio(0);
    }
  };

  // ---- pipelined k-loop over this subtile's active k-tiles ------------------------------
  int cur = mMe ? (__ffs(mMe)-1) : 16;
  if (cur < 16) issue(cur);
  while (cur < 16){
    const unsigned above = mMe & (0xfffffffeu << cur);
    const int nxt = above ? (__ffs(above)-1) : 16;
    __builtin_amdgcn_s_barrier();                  // all waves done READING prev tile (Ks/Vs/Ps)
    __builtin_amdgcn_sched_barrier(0);
    write_lds();                                   // implicit vmcnt wait on kreg/vreg here
    if (nxt < 16) issue(nxt);                      // issue-early: hides under compute below
    asm volatile("s_waitcnt lgkmcnt(0)" ::: "memory");   // my ds_writes visible
    __builtin_amdgcn_s_barrier();                  // everyone's writes visible
    __builtin_amdgcn_sched_barrier(0);
    compute(cur);
    cur = nxt;
  }

  // ---- epilogue -------------------------------------------------------------------------
  rs += __shfl_xor(rs, 16, 64);
  rs += __shfl_xor(rs, 32, 64);
  const float rinv = 1.0f / rs;
  const int qg = st*64 + w*16 + ln;
  #pragma unroll
  for (int ct=0;ct<4;++ct){
    short4v o4;
    #pragma unroll
    for (int r=0;r<4;++r) o4[r] = (short)f2b(acc[ct][r] * rinv);
    *(short4v*)&Ot[((size_t)b*S + qg)*1024 + h*64 + ct*16 + quad*4] = o4;
  }
}

extern "C" void kernel_launch(void* const* d_in, const int* in_sizes, int n_in,
                              void* d_out, int out_size, void* d_ws, size_t ws_size,
                              hipStream_t stream)
{
  const float* q   = (const float*)d_in[0];
  const float* k   = (const float*)d_in[1];
  const float* v   = (const float*)d_in[2];
  const float* qkm = (const float*)d_in[3];
  const float* km  = (const float*)d_in[4];
  const float* Wq  = (const float*)d_in[5];
  const float* bq  = (const float*)d_in[6];
  const float* Wk  = (const float*)d_in[7];
  const float* bk  = (const float*)d_in[8];
  const float* Wv  = (const float*)d_in[9];
  const float* bv  = (const float*)d_in[10];
  const float* Wo  = (const float*)d_in[11];
  const float* bo  = (const float*)d_in[12];
  float* out = (float*)d_out;

  const size_t nAct = (size_t)2*2048*1024;   // 4M elems per activation buffer
  const int   nW   = 1024*1024;

  u16* A0 = (u16*)d_ws;          // qT, later attn output Ot
  u16* A1 = A0 + nAct;           // kT
  u16* A2 = A1 + nAct;           // vT
  u16* A3 = A2 + nAct;           // Qb
  u16* A4 = A3 + nAct;           // Kb
  u16* A5 = A4 + nAct;           // Vb
  u16* W16 = A5 + nAct;          // Wq16|Wk16|Wv16|Wo16
  char* classes = (char*)(W16 + (size_t)4*nW);   // 2 KB
  u16* Wo16 = W16 + (size_t)3*nW;

  dim3 blk(256);
  prep      <<<dim3(7168), blk, 0, stream>>>(q, k, v, qkm, km, Wq, Wk, Wv, Wo,
                                             W16, classes, A0, A1, A2);
  proj      <<<dim3(768),  blk, 0, stream>>>(A0, A1, A2, W16, bq, bk, bv, A3, A4, A5);
  attn      <<<dim3(1024), blk, 0, stream>>>(A3, A4, A5, qkm, km, classes, A0);
  gemm_out64<<<dim3(16,16,2), blk, 0, stream>>>(Wo16, A0, bo, out);
}

// Round 12
// 234.089 us; speedup vs baseline: 1.0540x; 1.0540x over previous
//
#include <hip/hip_runtime.h>
#include <hip/hip_bf16.h>
#include <stdint.h>

typedef unsigned short u16;
typedef __attribute__((ext_vector_type(8))) short short8;
typedef __attribute__((ext_vector_type(4))) short short4v;
typedef __attribute__((ext_vector_type(4))) float f32x4;

#define MFMA16(a,b,c) __builtin_amdgcn_mfma_f32_16x16x32_bf16((a),(b),(c),0,0,0)
#define EXP2F(x) __builtin_amdgcn_exp2f(x)

typedef const __attribute__((address_space(1))) void glb_void;
typedef __attribute__((address_space(3))) void lds_void;

__device__ __forceinline__ u16 f2b(float f){
  unsigned u = __float_as_uint(f);
  u += 0x7fffu + ((u>>16)&1u);
  return (u16)(u>>16);
}
__device__ __forceinline__ unsigned pack_bf16(float a, float b){
  __hip_bfloat162 h = __float22bfloat162_rn(make_float2(a,b));
  unsigned u; __builtin_memcpy(&u, &h, 4); return u;
}
__device__ __forceinline__ void gld16(const void* g, void* l){
  __builtin_amdgcn_global_load_lds((glb_void*)g, (lds_void*)l, 16, 0, 0);
}

// ---- swizzled layout: LDS[row][c] = G[row][ (c/8 ^ (row&7))*8 + c%8 ] ----
__device__ __forceinline__ const short8* frag64(const u16* lds, int row, int c16){
  return (const short8*)(lds + row*64 + ((c16 ^ (row&7))<<3));
}
__device__ __forceinline__ const short8* frag128(const u16* lds, int row, int c16){
  return (const short8*)(lds + row*128 + ((c16 ^ (row&15))<<3));
}

// ================= PREP: weight cvt + mask classes + q/k/v transposes, one dispatch =======
// mask classes: 0 = all-zero, 2 = all-masked, 3 = EXACT causal, 1 = other (fallback load).
__global__ __launch_bounds__(256) void prep(
    const float* __restrict__ q, const float* __restrict__ k, const float* __restrict__ v,
    const float* __restrict__ qkm, const float* __restrict__ km,
    const float* __restrict__ Wq, const float* __restrict__ Wk,
    const float* __restrict__ Wv, const float* __restrict__ Wo,
    u16* __restrict__ W16, char* __restrict__ classes,
    u16* __restrict__ qT, u16* __restrict__ kT, u16* __restrict__ vT)
{
  __shared__ __align__(16) float t[64][72];
  const int bx = blockIdx.x, tid = threadIdx.x;
  const int S = 2048, E = 1024, nW = E*E;
  const float NEG = -1e4f;

  if (bx < 2048){                      // ---- weight convert ----
    const int sel = bx>>9, blk = bx&511;
    const float* src = sel==0?Wq : sel==1?Wk : sel==2?Wv : Wo;
    const float sc = (sel==0) ? 0.18033688f : 1.0f;   // 0.125 * log2(e)
    u16* dst = W16 + (size_t)sel*nW;
    int i = (blk*256 + tid)*8;
    float4 a = *(const float4*)(src+i);
    float4 b = *(const float4*)(src+i+4);
    short8 o;
    o[0]=(short)f2b(a.x*sc); o[1]=(short)f2b(a.y*sc); o[2]=(short)f2b(a.z*sc); o[3]=(short)f2b(a.w*sc);
    o[4]=(short)f2b(b.x*sc); o[5]=(short)f2b(b.y*sc); o[6]=(short)f2b(b.z*sc); o[7]=(short)f2b(b.w*sc);
    *(short8*)(dst+i) = o;
  } else if (bx < 4096){               // ---- mask tile classification (64x64) ----
    const int tt = bx - 2048;
    const int b = tt>>10, qi = (tt>>5)&31, ki = tt&31;
    const int k0 = ki*64, q0 = qi*64;
    int az = 1, an = 1, ac = 1;
    #pragma unroll
    for (int p=0;p<4;++p){
      int e = tid + p*256;
      int row = e>>4, c4 = (e&15)*4;
      const int kg = k0 + row;
      float kmv = km[(size_t)b*S + kg];
      float4 mv = *(const float4*)&qkm[((size_t)b*S + kg)*S + q0 + c4];
      mv.x += kmv; mv.y += kmv; mv.z += kmv; mv.w += kmv;
      az &= (mv.x==0.f) & (mv.y==0.f) & (mv.z==0.f) & (mv.w==0.f);
      an &= (mv.x<-1e3f) & (mv.y<-1e3f) & (mv.z<-1e3f) & (mv.w<-1e3f);
      const float e0 = (kg > q0+c4+0) ? NEG : 0.f;
      const float e1 = (kg > q0+c4+1) ? NEG : 0.f;
      const float e2 = (kg > q0+c4+2) ? NEG : 0.f;
      const float e3 = (kg > q0+c4+3) ? NEG : 0.f;
      ac &= (mv.x==e0) & (mv.y==e1) & (mv.z==e2) & (mv.w==e3);
    }
    const int az_all = __syncthreads_and(az);
    const int an_all = __syncthreads_and(an);
    const int ac_all = __syncthreads_and(ac);
    if (tid==0)
      classes[((size_t)b*32 + qi)*32 + ki] =
          an_all ? 2 : (az_all ? 0 : (ac_all ? 3 : 1));
  } else {                             // ---- transpose+convert q/k/v ----
    const int tt = bx - 4096;
    const int tensor = tt>>10, r = tt&1023;
    const int b = r>>9, rr = r&511;
    const int c0 = (rr>>5)*64, s0 = (rr&31)*64;
    const float* x = tensor==0 ? q : tensor==1 ? k : v;
    u16* xt = tensor==0 ? qT : tensor==1 ? kT : vT;
    #pragma unroll
    for (int p=0;p<4;++p){
      int e = tid + p*256;
      int row = e>>4, c4 = (e&15)*4;
      *(float4*)&t[row][c4] = *(const float4*)&x[((size_t)b*E + c0 + row)*S + s0 + c4];
    }
    __syncthreads();
    #pragma unroll
    for (int p=0;p<2;++p){
      int e = tid + p*256;
      int row = e>>3, col8 = (e&7)*8;
      short8 o;
      #pragma unroll
      for (int u=0;u<8;++u) o[u] = (short)f2b(t[col8+u][row]);
      *(short8*)&xt[((size_t)b*S + s0 + row)*E + c0 + col8] = o;
    }
  }
}

// ---------------- GEMM core: C[M][N] = A[M][K]*Bt[N][K]^T + bias*bscale -------------------
template<bool F32OUT>
__device__ __forceinline__ void gemm_core(
    const u16* __restrict__ A, const u16* __restrict__ Bt, const float* __restrict__ bias,
    float bscale, void* __restrict__ Cv, size_t cbase, int N, int K, int bias_on_m,
    int m0, int n0, u16* As, u16* Bs)
{
  const int tid = threadIdx.x, w = tid>>6, lane = tid&63;
  const int ln = lane&15, quad = lane>>4;
  const int m0w = (w>>1)*64, n0w = (w&1)*64;
  const int sub = lane>>3, gcol = ((lane&7)^sub)<<3;
  f32x4 acc[4][4];
  #pragma unroll
  for(int i=0;i<4;++i)
    #pragma unroll
    for(int j=0;j<4;++j) acc[i][j] = f32x4{0.f,0.f,0.f,0.f};

  short8 areg[4], breg[4];
  auto issue = [&](int kc){
    #pragma unroll
    for (int i=0;i<4;++i){
      const int r0 = (w*4+i)*8 + sub;
      areg[i] = *(const short8*)(A  + (size_t)(m0 + r0)*K + kc + gcol);
      breg[i] = *(const short8*)(Bt + (size_t)(n0 + r0)*K + kc + gcol);
    }
  };
  auto write_lds = [&](){
    #pragma unroll
    for (int i=0;i<4;++i){
      *(short8*)&As[(w*4+i)*512 + lane*8] = areg[i];
      *(short8*)&Bs[(w*4+i)*512 + lane*8] = breg[i];
    }
  };

  issue(0);
  for (int kc=0; kc<K; kc+=64){
    __builtin_amdgcn_s_barrier();                  // all waves done reading prev tile
    __builtin_amdgcn_sched_barrier(0);
    write_lds();                                   // implicit vmcnt wait on areg/breg
    if (kc+64 < K) issue(kc+64);                   // overlap next loads with compute
    asm volatile("s_waitcnt lgkmcnt(0)" ::: "memory");
    __builtin_amdgcn_s_barrier();
    __builtin_amdgcn_sched_barrier(0);
    #pragma unroll
    for (int kk=0; kk<64; kk+=32){
      const int c16 = (kk>>3) + quad;
      short8 af[4], bf[4];
      #pragma unroll
      for (int mt=0;mt<4;++mt) af[mt] = *frag64(As, m0w+mt*16+ln, c16);
      #pragma unroll
      for (int nt=0;nt<4;++nt) bf[nt] = *frag64(Bs, n0w+nt*16+ln, c16);
      #pragma unroll
      for (int mt=0;mt<4;++mt)
        #pragma unroll
        for (int nt=0;nt<4;++nt)
          acc[mt][nt] = MFMA16(af[mt], bf[nt], acc[mt][nt]);
    }
  }
  #pragma unroll
  for (int mt=0;mt<4;++mt){
    #pragma unroll
    for (int nt=0;nt<4;++nt){
      const int col = n0 + n0w + nt*16 + ln;
      const float bn = bias_on_m ? 0.f : bias[col]*bscale;
      #pragma unroll
      for (int r=0;r<4;++r){
        const int row = m0 + m0w + mt*16 + quad*4 + r;
        const float bb = bias_on_m ? bias[row]*bscale : bn;
        const float val = acc[mt][nt][r] + bb;
        const size_t idx = cbase + (size_t)row*N + col;
        if (F32OUT) ((float*)Cv)[idx] = val;
        else        ((u16*)Cv)[idx]   = f2b(val);
      }
    }
  }
}

// ================= PROJ: Q,K,V projections in one uniform dispatch (768 blocks) ===========
__global__ __launch_bounds__(256,2) void proj(
    const u16* __restrict__ qT, const u16* __restrict__ kT, const u16* __restrict__ vT,
    const u16* __restrict__ W16,
    const float* __restrict__ bq, const float* __restrict__ bk, const float* __restrict__ bv,
    u16* __restrict__ Qb, u16* __restrict__ Kb, u16* __restrict__ Vb)
{
  __shared__ __align__(16) u16 As[128*64];
  __shared__ __align__(16) u16 Bs[128*64];
  const int bx = blockIdx.x;
  const int zone = bx>>7, r = bx&127;
  const size_t sSE = (size_t)2048*1024;
  const int nW = 1024*1024;
  if (zone < 4){
    const int sel = zone>>1, b = zone&1;
    const int m0 = (r>>3)*128, n0 = (r&7)*128;
    gemm_core<false>((sel? kT : qT) + b*sSE, W16 + (size_t)sel*nW, sel? bk : bq,
                     sel? 1.0f : 0.18033688f, sel? Kb : Qb, b*sSE,
                     1024, 1024, 0, m0, n0, As, Bs);
  } else {
    const int b = zone&1;
    const int m0 = (r>>4)*128, n0 = (r&15)*128;
    gemm_core<false>(W16 + (size_t)2*nW, vT + b*sSE, bv,
                     1.0f, Vb, b*sSE,
                     2048, 1024, 1, m0, n0, As, Bs);
  }
}

// ================= OUT GEMM: 64x128 tiles, 512 blocks = 2/CU, reg-staged pipeline =========
__global__ __launch_bounds__(256,3) void gemm_out64(
    const u16* __restrict__ Wo16, const u16* __restrict__ At, const float* __restrict__ bo,
    float* __restrict__ out)
{
  __shared__ __align__(16) u16 As[64*64];
  __shared__ __align__(16) u16 Bs[128*64];
  const int b = blockIdx.z;
  const int m0 = blockIdx.y*64, n0 = blockIdx.x*128;
  const size_t sSE = (size_t)2048*1024;
  const int K = 1024, N = 2048;
  const u16* Bt = At + b*sSE;
  const int tid = threadIdx.x, w = tid>>6, lane = tid&63;
  const int ln = lane&15, quad = lane>>4;
  const int m0w = (w>>1)*32, n0w = (w&1)*64;
  const int sub = lane>>3, gcol = ((lane&7)^sub)<<3;
  f32x4 acc[2][4];
  #pragma unroll
  for(int i=0;i<2;++i)
    #pragma unroll
    for(int j=0;j<4;++j) acc[i][j] = f32x4{0.f,0.f,0.f,0.f};

  short8 areg[2], breg[4];
  auto issue = [&](int kc){
    #pragma unroll
    for (int i=0;i<2;++i){
      const int r0 = (w*2+i)*8 + sub;
      areg[i] = *(const short8*)(Wo16 + (size_t)(m0 + r0)*K + kc + gcol);
    }
    #pragma unroll
    for (int i=0;i<4;++i){
      const int r0 = (w*4+i)*8 + sub;
      breg[i] = *(const short8*)(Bt + (size_t)(n0 + r0)*K + kc + gcol);
    }
  };
  auto write_lds = [&](){
    #pragma unroll
    for (int i=0;i<2;++i)
      *(short8*)&As[(w*2+i)*512 + lane*8] = areg[i];
    #pragma unroll
    for (int i=0;i<4;++i)
      *(short8*)&Bs[(w*4+i)*512 + lane*8] = breg[i];
  };

  issue(0);
  for (int kc=0; kc<K; kc+=64){
    __builtin_amdgcn_s_barrier();
    __builtin_amdgcn_sched_barrier(0);
    write_lds();
    if (kc+64 < K) issue(kc+64);
    asm volatile("s_waitcnt lgkmcnt(0)" ::: "memory");
    __builtin_amdgcn_s_barrier();
    __builtin_amdgcn_sched_barrier(0);
    #pragma unroll
    for (int kk=0; kk<64; kk+=32){
      const int c16 = (kk>>3) + quad;
      short8 af[2], bf[4];
      #pragma unroll
      for (int mt=0;mt<2;++mt) af[mt] = *frag64(As, m0w+mt*16+ln, c16);
      #pragma unroll
      for (int nt=0;nt<4;++nt) bf[nt] = *frag64(Bs, n0w+nt*16+ln, c16);
      #pragma unroll
      for (int mt=0;mt<2;++mt)
        #pragma unroll
        for (int nt=0;nt<4;++nt)
          acc[mt][nt] = MFMA16(af[mt], bf[nt], acc[mt][nt]);
    }
  }
  #pragma unroll
  for (int mt=0;mt<2;++mt){
    #pragma unroll
    for (int nt=0;nt<4;++nt){
      const int col = n0 + n0w + nt*16 + ln;
      #pragma unroll
      for (int r=0;r<4;++r){
        const int row = m0 + m0w + mt*16 + quad*4 + r;
        out[b*sSE + (size_t)row*N + col] = acc[mt][nt][r] + bo[row];
      }
    }
  }
}

// ================= fused flash attention (R10 structure + XCD-grouped (b,h)) ==============
// one 64-row q-subtile per 256-thread block, 1024 blocks. R10's per-wave LDS P^T transpose
// (8 b64 writes + 4 b128 reads replace 32 bpermutes) -- best measured attn (43.6 us).
// R12: bh = (bx&7)*4 + ((bx>>3)&3) groups blocks sharing (b,h) onto the same XCD residue
// class (4 K/V panels x 1MB = one 4MB XCD L2); st = 31-(bx>>5) keeps heavy-first order.
// Pure work permutation -- affects only L2 locality.
__global__ __launch_bounds__(256,2) void attn(
    const u16* __restrict__ Qb, const u16* __restrict__ Kb, const u16* __restrict__ Vb,
    const float* __restrict__ qk_mask, const float* __restrict__ k_mask,
    const char* __restrict__ classes, u16* __restrict__ Ot)
{
  __shared__ __align__(16) u16 Ks[128*64];
  __shared__ __align__(16) u16 Vs[64*128];
  __shared__ __align__(16) u16 Ps[4*16*128];      // per-wave P^T, 4 KB each
  const int bx = blockIdx.x;
  const int st = 31 - (bx>>5);           // q-subtile 0..31, heavy (high-st) first
  const int bh = (bx&7)*4 + ((bx>>3)&3); // XCD-grouped (b,h): same bx%8 -> same 4 panels
  const int b = bh & 1, h = bh >> 1;
  const int tid = threadIdx.x, w = tid>>6, lane = tid&63;
  const int ln = lane&15, quad = lane>>4;
  const int S = 2048;
  const float LOG2E = 1.44269504f, C2 = 16.0f;

  const int qg = st*64 + w*16 + ln;
  short8 qf[2];
  #pragma unroll
  for (int kkI=0;kkI<2;++kkI)
    qf[kkI] = *(const short8*)&Qb[((size_t)b*S + qg)*1024 + h*64 + kkI*32 + quad*8];

  const char* cl = classes + ((size_t)b*32 + st)*32;
  unsigned mMe=0;
  #pragma unroll
  for (int kt=0;kt<16;++kt)
    if (!((cl[2*kt]==2) & (cl[2*kt+1]==2))) mMe |= 1u<<kt;

  float rs = 0.f;
  f32x4 acc[4];
  #pragma unroll
  for (int ct=0;ct<4;++ct) acc[ct] = f32x4{0.f,0.f,0.f,0.f};

  // per-wave P^T base: row = ln (256 B/row), XOR-swizzle on the k-byte-offset
  char* Pbase = (char*)(Ps + w*16*128) + ln*256;
  const int rsw = (ln&7)<<4;

  // ---- reg staging (LDS linear, source pre-swizzled), 4 waves --------------------------
  const u16* gK = Kb + ((size_t)b*S)*1024 + h*64;        // K rows, stride 1024
  const u16* gV = Vb + ((size_t)b*1024 + h*64)*S;        // V rows (64 of them), stride S
  const int subK = lane>>3, cK = ((lane&7)^subK)<<3;
  const int subV = lane>>4, cV0 = lane&15;

  short8 kreg[4], vreg[4];
  auto issue = [&](int kt){
    const int k0 = kt*128;
    #pragma unroll
    for (int i=0;i<4;++i){
      const int r = (w*4+i)*8 + subK;                    // K row in tile (0..127)
      kreg[i] = *(const short8*)(gK + (size_t)(k0 + r)*1024 + cK);
    }
    #pragma unroll
    for (int i=0;i<4;++i){
      const int row = (w*4+i)*4 + subV;                  // V row (0..63)
      vreg[i] = *(const short8*)(gV + (size_t)row*S + k0 + ((cV0 ^ (row&15))<<3));
    }
  };
  auto write_lds = [&](){
    #pragma unroll
    for (int i=0;i<4;++i)
      *(short8*)&Ks[(w*4+i)*512 + lane*8] = kreg[i];     // rows (w*4+i)*8.., linear
    #pragma unroll
    for (int i=0;i<4;++i)
      *(short8*)&Vs[(w*4+i)*512 + lane*8] = vreg[i];     // rows (w*4+i)*4.., linear
  };

  auto compute = [&](int kt){
    const char c0 = cl[2*kt], c1 = cl[2*kt+1];
    const bool nomask = (c0|c1)==0;
    const bool analytic = (c0!=1) & (c1!=1);             // classes in {0,2,3}: causal form
    const int k0 = kt*128;
    #pragma unroll
    for (int t=0;t<8;++t){
      f32x4 s = f32x4{0.f,0.f,0.f,0.f};
      #pragma unroll
      for (int kkI=0;kkI<2;++kkI)
        s = MFMA16(*frag64(Ks, t*16+ln, kkI*4 + quad), qf[kkI], s);
      float e[4];
      if (nomask){
        #pragma unroll
        for (int r=0;r<4;++r) e[r] = EXP2F(s[r] - C2);
      } else if (analytic){
        #pragma unroll
        for (int r=0;r<4;++r){
          const int kg = k0 + t*16 + quad*4 + r;
          e[r] = (kg <= qg) ? EXP2F(s[r] - C2) : 0.f;
        }
      } else {
        #pragma unroll
        for (int r=0;r<4;++r){
          const int kg = k0 + t*16 + quad*4 + r;
          const float m = qk_mask[((size_t)b*S + kg)*S + qg] + k_mask[(size_t)b*S + kg];
          e[r] = EXP2F(fmaf(m, LOG2E, s[r]) - C2);
        }
      }
      rs += (e[0]+e[1]) + (e[2]+e[3]);
      uint2 pp;
      pp.x = pack_bf16(e[0], e[1]);
      pp.y = pack_bf16(e[2], e[3]);
      *(uint2*)(Pbase + ((t*32 + quad*8) ^ rsw)) = pp;   // P^T[ln][t*16+quad*4 ..+3]
    }
    // compiler inserts lgkmcnt for the write->read dependency (same LDS region)
    #pragma unroll
    for (int c=0;c<4;++c){
      const short8 pf = *(const short8*)(Pbase + ((c*64 + quad*16) ^ rsw));
      __builtin_amdgcn_s_setprio(1);
      #pragma unroll
      for (int ct=0;ct<4;++ct)
        acc[ct] = MFMA16(*frag128(Vs, ct*16+ln, c*4 + quad), pf, acc[ct]);
      __builtin_amdgcn_s_setprio(0);
    }
  };

  // ---- pipelined k-loop over this subtile's active k-tiles ------------------------------
  int cur = mMe ? (__ffs(mMe)-1) : 16;
  if (cur < 16) issue(cur);
  while (cur < 16){
    const unsigned above = mMe & (0xfffffffeu << cur);
    const int nxt = above ? (__ffs(above)-1) : 16;
    __builtin_amdgcn_s_barrier();                  // all waves done READING prev tile
    __builtin_amdgcn_sched_barrier(0);
    write_lds();                                   // implicit vmcnt wait on kreg/vreg here
    if (nxt < 16) issue(nxt);                      // issue-early: hides under compute below
    asm volatile("s_waitcnt lgkmcnt(0)" ::: "memory");   // my ds_writes visible
    __builtin_amdgcn_s_barrier();                  // everyone's writes visible
    __builtin_amdgcn_sched_barrier(0);
    compute(cur);
    cur = nxt;
  }

  // ---- epilogue -------------------------------------------------------------------------
  rs += __shfl_xor(rs, 16, 64);
  rs += __shfl_xor(rs, 32, 64);
  const float rinv = 1.0f / rs;
  #pragma unroll
  for (int ct=0;ct<4;++ct){
    short4v o4;
    #pragma unroll
    for (int r=0;r<4;++r) o4[r] = (short)f2b(acc[ct][r] * rinv);
    *(short4v*)&Ot[((size_t)b*S + qg)*1024 + h*64 + ct*16 + quad*4] = o4;
  }
}

extern "C" void kernel_launch(void* const* d_in, const int* in_sizes, int n_in,
                              void* d_out, int out_size, void* d_ws, size_t ws_size,
                              hipStream_t stream)
{
  const float* q   = (const float*)d_in[0];
  const float* k   = (const float*)d_in[1];
  const float* v   = (const float*)d_in[2];
  const float* qkm = (const float*)d_in[3];
  const float* km  = (const float*)d_in[4];
  const float* Wq  = (const float*)d_in[5];
  const float* bq  = (const float*)d_in[6];
  const float* Wk  = (const float*)d_in[7];
  const float* bk  = (const float*)d_in[8];
  const float* Wv  = (const float*)d_in[9];
  const float* bv  = (const float*)d_in[10];
  const float* Wo  = (const float*)d_in[11];
  const float* bo  = (const float*)d_in[12];
  float* out = (float*)d_out;

  const size_t nAct = (size_t)2*2048*1024;   // 4M elems per activation buffer
  const int   nW   = 1024*1024;

  u16* A0 = (u16*)d_ws;          // qT, later attn output Ot
  u16* A1 = A0 + nAct;           // kT
  u16* A2 = A1 + nAct;           // vT
  u16* A3 = A2 + nAct;           // Qb
  u16* A4 = A3 + nAct;           // Kb
  u16* A5 = A4 + nAct;           // Vb
  u16* W16 = A5 + nAct;          // Wq16|Wk16|Wv16|Wo16
  char* classes = (char*)(W16 + (size_t)4*nW);   // 2 KB
  u16* Wo16 = W16 + (size_t)3*nW;

  dim3 blk(256);
  prep      <<<dim3(7168), blk, 0, stream>>>(q, k, v, qkm, km, Wq, Wk, Wv, Wo,
                                             W16, classes, A0, A1, A2);
  proj      <<<dim3(768),  blk, 0, stream>>>(A0, A1, A2, W16, bq, bk, bv, A3, A4, A5);
  attn      <<<dim3(1024), blk, 0, stream>>>(A3, A4, A5, qkm, km, classes, A0);
  gemm_out64<<<dim3(16,16,2), blk, 0, stream>>>(Wo16, A0, bo, out);
}

// Round 13
// 226.600 us; speedup vs baseline: 1.0889x; 1.0330x over previous
//
#include <hip/hip_runtime.h>
#include <hip/hip_bf16.h>
#include <stdint.h>

typedef unsigned short u16;
typedef __attribute__((ext_vector_type(8))) short short8;
typedef __attribute__((ext_vector_type(4))) short short4v;
typedef __attribute__((ext_vector_type(4))) float f32x4;

#define MFMA16(a,b,c) __builtin_amdgcn_mfma_f32_16x16x32_bf16((a),(b),(c),0,0,0)
#define EXP2F(x) __builtin_amdgcn_exp2f(x)

typedef const __attribute__((address_space(1))) void glb_void;
typedef __attribute__((address_space(3))) void lds_void;

__device__ __forceinline__ u16 f2b(float f){
  unsigned u = __float_as_uint(f);
  u += 0x7fffu + ((u>>16)&1u);
  return (u16)(u>>16);
}
__device__ __forceinline__ unsigned pack_bf16(float a, float b){
  __hip_bfloat162 h = __float22bfloat162_rn(make_float2(a,b));
  unsigned u; __builtin_memcpy(&u, &h, 4); return u;
}
__device__ __forceinline__ void gld16(const void* g, void* l){
  __builtin_amdgcn_global_load_lds((glb_void*)g, (lds_void*)l, 16, 0, 0);
}

// ---- swizzled staging (gld16): LDS[row][c] = G[row][ (c/8 ^ (row&7))*8 + c%8 ] ----
// m151: at 128^2 tiles global_load_lds beats reg-staging (874 vs 646 TF) -- R13 reverts
// proj/gemm_out to this path (R8's reg-staging also cost a resident block via VGPR).
__device__ __forceinline__ void stage128x64_sw(const u16* g, u16* lds, int gstride, int w, int lane){
  const int sub = lane>>3, c16 = lane&7;
  const int gcol = (c16 ^ sub)<<3;
  #pragma unroll
  for (int i=0;i<4;++i){
    int r0 = (w*4+i)*8;
    gld16(g + (size_t)(r0 + sub)*gstride + gcol, lds + r0*64);
  }
}
__device__ __forceinline__ void stage64x64_sw(const u16* g, u16* lds, int gstride, int w, int lane){
  const int sub = lane>>3, c16 = lane&7;
  const int gcol = (c16 ^ sub)<<3;
  #pragma unroll
  for (int i=0;i<2;++i){
    int r0 = (w*2+i)*8;
    gld16(g + (size_t)(r0 + sub)*gstride + gcol, lds + r0*64);
  }
}
__device__ __forceinline__ const short8* frag64(const u16* lds, int row, int c16){
  return (const short8*)(lds + row*64 + ((c16 ^ (row&7))<<3));
}
__device__ __forceinline__ const short8* frag128(const u16* lds, int row, int c16){
  return (const short8*)(lds + row*128 + ((c16 ^ (row&15))<<3));
}

// ================= PREP: weight cvt + mask classes + q/k/v transposes, one dispatch =======
// mask classes: 0 = all-zero, 2 = all-masked, 3 = EXACT causal, 1 = other (fallback load).
__global__ __launch_bounds__(256) void prep(
    const float* __restrict__ q, const float* __restrict__ k, const float* __restrict__ v,
    const float* __restrict__ qkm, const float* __restrict__ km,
    const float* __restrict__ Wq, const float* __restrict__ Wk,
    const float* __restrict__ Wv, const float* __restrict__ Wo,
    u16* __restrict__ W16, char* __restrict__ classes,
    u16* __restrict__ qT, u16* __restrict__ kT, u16* __restrict__ vT)
{
  __shared__ __align__(16) float t[64][72];
  const int bx = blockIdx.x, tid = threadIdx.x;
  const int S = 2048, E = 1024, nW = E*E;
  const float NEG = -1e4f;

  if (bx < 2048){                      // ---- weight convert ----
    const int sel = bx>>9, blk = bx&511;
    const float* src = sel==0?Wq : sel==1?Wk : sel==2?Wv : Wo;
    const float sc = (sel==0) ? 0.18033688f : 1.0f;   // 0.125 * log2(e)
    u16* dst = W16 + (size_t)sel*nW;
    int i = (blk*256 + tid)*8;
    float4 a = *(const float4*)(src+i);
    float4 b = *(const float4*)(src+i+4);
    short8 o;
    o[0]=(short)f2b(a.x*sc); o[1]=(short)f2b(a.y*sc); o[2]=(short)f2b(a.z*sc); o[3]=(short)f2b(a.w*sc);
    o[4]=(short)f2b(b.x*sc); o[5]=(short)f2b(b.y*sc); o[6]=(short)f2b(b.z*sc); o[7]=(short)f2b(b.w*sc);
    *(short8*)(dst+i) = o;
  } else if (bx < 4096){               // ---- mask tile classification (64x64) ----
    const int tt = bx - 2048;
    const int b = tt>>10, qi = (tt>>5)&31, ki = tt&31;
    const int k0 = ki*64, q0 = qi*64;
    int az = 1, an = 1, ac = 1;
    #pragma unroll
    for (int p=0;p<4;++p){
      int e = tid + p*256;
      int row = e>>4, c4 = (e&15)*4;
      const int kg = k0 + row;
      float kmv = km[(size_t)b*S + kg];
      float4 mv = *(const float4*)&qkm[((size_t)b*S + kg)*S + q0 + c4];
      mv.x += kmv; mv.y += kmv; mv.z += kmv; mv.w += kmv;
      az &= (mv.x==0.f) & (mv.y==0.f) & (mv.z==0.f) & (mv.w==0.f);
      an &= (mv.x<-1e3f) & (mv.y<-1e3f) & (mv.z<-1e3f) & (mv.w<-1e3f);
      const float e0 = (kg > q0+c4+0) ? NEG : 0.f;
      const float e1 = (kg > q0+c4+1) ? NEG : 0.f;
      const float e2 = (kg > q0+c4+2) ? NEG : 0.f;
      const float e3 = (kg > q0+c4+3) ? NEG : 0.f;
      ac &= (mv.x==e0) & (mv.y==e1) & (mv.z==e2) & (mv.w==e3);
    }
    const int az_all = __syncthreads_and(az);
    const int an_all = __syncthreads_and(an);
    const int ac_all = __syncthreads_and(ac);
    if (tid==0)
      classes[((size_t)b*32 + qi)*32 + ki] =
          an_all ? 2 : (az_all ? 0 : (ac_all ? 3 : 1));
  } else {                             // ---- transpose+convert q/k/v ----
    const int tt = bx - 4096;
    const int tensor = tt>>10, r = tt&1023;
    const int b = r>>9, rr = r&511;
    const int c0 = (rr>>5)*64, s0 = (rr&31)*64;
    const float* x = tensor==0 ? q : tensor==1 ? k : v;
    u16* xt = tensor==0 ? qT : tensor==1 ? kT : vT;
    #pragma unroll
    for (int p=0;p<4;++p){
      int e = tid + p*256;
      int row = e>>4, c4 = (e&15)*4;
      *(float4*)&t[row][c4] = *(const float4*)&x[((size_t)b*E + c0 + row)*S + s0 + c4];
    }
    __syncthreads();
    #pragma unroll
    for (int p=0;p<2;++p){
      int e = tid + p*256;
      int row = e>>3, col8 = (e&7)*8;
      short8 o;
      #pragma unroll
      for (int u=0;u<8;++u) o[u] = (short)f2b(t[col8+u][row]);
      *(short8*)&xt[((size_t)b*S + s0 + row)*E + c0 + col8] = o;
    }
  }
}

// ---------------- GEMM core (R4/R6-proven): gld16 staging + __syncthreads loop ------------
template<bool F32OUT>
__device__ __forceinline__ void gemm_core(
    const u16* __restrict__ A, const u16* __restrict__ Bt, const float* __restrict__ bias,
    float bscale, void* __restrict__ Cv, size_t cbase, int N, int K, int bias_on_m,
    int m0, int n0, u16* As, u16* Bs)
{
  const int tid = threadIdx.x, w = tid>>6, lane = tid&63;
  const int ln = lane&15, quad = lane>>4;
  const int m0w = (w>>1)*64, n0w = (w&1)*64;
  f32x4 acc[4][4];
  #pragma unroll
  for(int i=0;i<4;++i)
    #pragma unroll
    for(int j=0;j<4;++j) acc[i][j] = f32x4{0.f,0.f,0.f,0.f};

  for (int kc=0; kc<K; kc+=64){
    __syncthreads();
    stage128x64_sw(A  + (size_t)m0*K + kc, As, K, w, lane);
    stage128x64_sw(Bt + (size_t)n0*K + kc, Bs, K, w, lane);
    __syncthreads();
    #pragma unroll
    for (int kk=0; kk<64; kk+=32){
      const int c16 = (kk>>3) + quad;
      short8 af[4], bf[4];
      #pragma unroll
      for (int mt=0;mt<4;++mt) af[mt] = *frag64(As, m0w+mt*16+ln, c16);
      #pragma unroll
      for (int nt=0;nt<4;++nt) bf[nt] = *frag64(Bs, n0w+nt*16+ln, c16);
      #pragma unroll
      for (int mt=0;mt<4;++mt)
        #pragma unroll
        for (int nt=0;nt<4;++nt)
          acc[mt][nt] = MFMA16(af[mt], bf[nt], acc[mt][nt]);
    }
  }
  #pragma unroll
  for (int mt=0;mt<4;++mt){
    #pragma unroll
    for (int nt=0;nt<4;++nt){
      const int col = n0 + n0w + nt*16 + ln;
      const float bn = bias_on_m ? 0.f : bias[col]*bscale;
      #pragma unroll
      for (int r=0;r<4;++r){
        const int row = m0 + m0w + mt*16 + quad*4 + r;
        const float bb = bias_on_m ? bias[row]*bscale : bn;
        const float val = acc[mt][nt][r] + bb;
        const size_t idx = cbase + (size_t)row*N + col;
        if (F32OUT) ((float*)Cv)[idx] = val;
        else        ((u16*)Cv)[idx]   = f2b(val);
      }
    }
  }
}

// ================= PROJ: Q,K,V projections in one uniform dispatch (768 blocks) ===========
// zone = bx>>7: 0..3 = (Q|K) x batch -> C[s][o]; 4..5 = V x batch -> C[o][s]
__global__ __launch_bounds__(256,3) void proj(
    const u16* __restrict__ qT, const u16* __restrict__ kT, const u16* __restrict__ vT,
    const u16* __restrict__ W16,
    const float* __restrict__ bq, const float* __restrict__ bk, const float* __restrict__ bv,
    u16* __restrict__ Qb, u16* __restrict__ Kb, u16* __restrict__ Vb)
{
  __shared__ __align__(16) u16 As[128*64];
  __shared__ __align__(16) u16 Bs[128*64];
  const int bx = blockIdx.x;
  const int zone = bx>>7, r = bx&127;
  const size_t sSE = (size_t)2048*1024;
  const int nW = 1024*1024;
  if (zone < 4){
    const int sel = zone>>1, b = zone&1;
    const int m0 = (r>>3)*128, n0 = (r&7)*128;
    gemm_core<false>((sel? kT : qT) + b*sSE, W16 + (size_t)sel*nW, sel? bk : bq,
                     sel? 1.0f : 0.18033688f, sel? Kb : Qb, b*sSE,
                     1024, 1024, 0, m0, n0, As, Bs);
  } else {
    const int b = zone&1;
    const int m0 = (r>>4)*128, n0 = (r&15)*128;
    gemm_core<false>(W16 + (size_t)2*nW, vT + b*sSE, bv,
                     1.0f, Vb, b*sSE,
                     2048, 1024, 1, m0, n0, As, Bs);
  }
}

// ================= OUT GEMM: 64x128 tiles, 512 blocks = 2/CU (R4-proven) ==================
__global__ __launch_bounds__(256,4) void gemm_out64(
    const u16* __restrict__ Wo16, const u16* __restrict__ At, const float* __restrict__ bo,
    float* __restrict__ out)
{
  __shared__ __align__(16) u16 As[64*64];
  __shared__ __align__(16) u16 Bs[128*64];
  const int b = blockIdx.z;
  const int m0 = blockIdx.y*64, n0 = blockIdx.x*128;
  const size_t sSE = (size_t)2048*1024;
  const int K = 1024, N = 2048;
  const u16* Bt = At + b*sSE;
  const int tid = threadIdx.x, w = tid>>6, lane = tid&63;
  const int ln = lane&15, quad = lane>>4;
  const int m0w = (w>>1)*32, n0w = (w&1)*64;
  f32x4 acc[2][4];
  #pragma unroll
  for(int i=0;i<2;++i)
    #pragma unroll
    for(int j=0;j<4;++j) acc[i][j] = f32x4{0.f,0.f,0.f,0.f};

  for (int kc=0; kc<K; kc+=64){
    __syncthreads();
    stage64x64_sw (Wo16 + (size_t)m0*K + kc, As, K, w, lane);
    stage128x64_sw(Bt   + (size_t)n0*K + kc, Bs, K, w, lane);
    __syncthreads();
    #pragma unroll
    for (int kk=0; kk<64; kk+=32){
      const int c16 = (kk>>3) + quad;
      short8 af[2], bf[4];
      #pragma unroll
      for (int mt=0;mt<2;++mt) af[mt] = *frag64(As, m0w+mt*16+ln, c16);
      #pragma unroll
      for (int nt=0;nt<4;++nt) bf[nt] = *frag64(Bs, n0w+nt*16+ln, c16);
      #pragma unroll
      for (int mt=0;mt<2;++mt)
        #pragma unroll
        for (int nt=0;nt<4;++nt)
          acc[mt][nt] = MFMA16(af[mt], bf[nt], acc[mt][nt]);
    }
  }
  #pragma unroll
  for (int mt=0;mt<2;++mt){
    #pragma unroll
    for (int nt=0;nt<4;++nt){
      const int col = n0 + n0w + nt*16 + ln;
      #pragma unroll
      for (int r=0;r<4;++r){
        const int row = m0 + m0w + mt*16 + quad*4 + r;
        out[b*sSE + (size_t)row*N + col] = acc[mt][nt][r] + bo[row];
      }
    }
  }
}

// ================= fused flash attention (R12 verbatim: R10 + XCD-grouped (b,h)) ==========
__global__ __launch_bounds__(256,2) void attn(
    const u16* __restrict__ Qb, const u16* __restrict__ Kb, const u16* __restrict__ Vb,
    const float* __restrict__ qk_mask, const float* __restrict__ k_mask,
    const char* __restrict__ classes, u16* __restrict__ Ot)
{
  __shared__ __align__(16) u16 Ks[128*64];
  __shared__ __align__(16) u16 Vs[64*128];
  __shared__ __align__(16) u16 Ps[4*16*128];      // per-wave P^T, 4 KB each
  const int bx = blockIdx.x;
  const int st = 31 - (bx>>5);           // q-subtile 0..31, heavy (high-st) first
  const int bh = (bx&7)*4 + ((bx>>3)&3); // XCD-grouped (b,h)
  const int b = bh & 1, h = bh >> 1;
  const int tid = threadIdx.x, w = tid>>6, lane = tid&63;
  const int ln = lane&15, quad = lane>>4;
  const int S = 2048;
  const float LOG2E = 1.44269504f, C2 = 16.0f;

  const int qg = st*64 + w*16 + ln;
  short8 qf[2];
  #pragma unroll
  for (int kkI=0;kkI<2;++kkI)
    qf[kkI] = *(const short8*)&Qb[((size_t)b*S + qg)*1024 + h*64 + kkI*32 + quad*8];

  const char* cl = classes + ((size_t)b*32 + st)*32;
  unsigned mMe=0;
  #pragma unroll
  for (int kt=0;kt<16;++kt)
    if (!((cl[2*kt]==2) & (cl[2*kt+1]==2))) mMe |= 1u<<kt;

  float rs = 0.f;
  f32x4 acc[4];
  #pragma unroll
  for (int ct=0;ct<4;++ct) acc[ct] = f32x4{0.f,0.f,0.f,0.f};

  // per-wave P^T base: row = ln (256 B/row), XOR-swizzle on the k-byte-offset
  char* Pbase = (char*)(Ps + w*16*128) + ln*256;
  const int rsw = (ln&7)<<4;

  // ---- reg staging (LDS linear, source pre-swizzled), 4 waves --------------------------
  const u16* gK = Kb + ((size_t)b*S)*1024 + h*64;        // K rows, stride 1024
  const u16* gV = Vb + ((size_t)b*1024 + h*64)*S;        // V rows (64 of them), stride S
  const int subK = lane>>3, cK = ((lane&7)^subK)<<3;
  const int subV = lane>>4, cV0 = lane&15;

  short8 kreg[4], vreg[4];
  auto issue = [&](int kt){
    const int k0 = kt*128;
    #pragma unroll
    for (int i=0;i<4;++i){
      const int r = (w*4+i)*8 + subK;                    // K row in tile (0..127)
      kreg[i] = *(const short8*)(gK + (size_t)(k0 + r)*1024 + cK);
    }
    #pragma unroll
    for (int i=0;i<4;++i){
      const int row = (w*4+i)*4 + subV;                  // V row (0..63)
      vreg[i] = *(const short8*)(gV + (size_t)row*S + k0 + ((cV0 ^ (row&15))<<3));
    }
  };
  auto write_lds = [&](){
    #pragma unroll
    for (int i=0;i<4;++i)
      *(short8*)&Ks[(w*4+i)*512 + lane*8] = kreg[i];     // rows (w*4+i)*8.., linear
    #pragma unroll
    for (int i=0;i<4;++i)
      *(short8*)&Vs[(w*4+i)*512 + lane*8] = vreg[i];     // rows (w*4+i)*4.., linear
  };

  auto compute = [&](int kt){
    const char c0 = cl[2*kt], c1 = cl[2*kt+1];
    const bool nomask = (c0|c1)==0;
    const bool analytic = (c0!=1) & (c1!=1);             // classes in {0,2,3}: causal form
    const int k0 = kt*128;
    #pragma unroll
    for (int t=0;t<8;++t){
      f32x4 s = f32x4{0.f,0.f,0.f,0.f};
      #pragma unroll
      for (int kkI=0;kkI<2;++kkI)
        s = MFMA16(*frag64(Ks, t*16+ln, kkI*4 + quad), qf[kkI], s);
      float e[4];
      if (nomask){
        #pragma unroll
        for (int r=0;r<4;++r) e[r] = EXP2F(s[r] - C2);
      } else if (analytic){
        #pragma unroll
        for (int r=0;r<4;++r){
          const int kg = k0 + t*16 + quad*4 + r;
          e[r] = (kg <= qg) ? EXP2F(s[r] - C2) : 0.f;
        }
      } else {
        #pragma unroll
        for (int r=0;r<4;++r){
          const int kg = k0 + t*16 + quad*4 + r;
          const float m = qk_mask[((size_t)b*S + kg)*S + qg] + k_mask[(size_t)b*S + kg];
          e[r] = EXP2F(fmaf(m, LOG2E, s[r]) - C2);
        }
      }
      rs += (e[0]+e[1]) + (e[2]+e[3]);
      uint2 pp;
      pp.x = pack_bf16(e[0], e[1]);
      pp.y = pack_bf16(e[2], e[3]);
      *(uint2*)(Pbase + ((t*32 + quad*8) ^ rsw)) = pp;   // P^T[ln][t*16+quad*4 ..+3]
    }
    // compiler inserts lgkmcnt for the write->read dependency (same LDS region)
    #pragma unroll
    for (int c=0;c<4;++c){
      const short8 pf = *(const short8*)(Pbase + ((c*64 + quad*16) ^ rsw));
      __builtin_amdgcn_s_setprio(1);
      #pragma unroll
      for (int ct=0;ct<4;++ct)
        acc[ct] = MFMA16(*frag128(Vs, ct*16+ln, c*4 + quad), pf, acc[ct]);
      __builtin_amdgcn_s_setprio(0);
    }
  };

  // ---- pipelined k-loop over this subtile's active k-tiles ------------------------------
  int cur = mMe ? (__ffs(mMe)-1) : 16;
  if (cur < 16) issue(cur);
  while (cur < 16){
    const unsigned above = mMe & (0xfffffffeu << cur);
    const int nxt = above ? (__ffs(above)-1) : 16;
    __builtin_amdgcn_s_barrier();                  // all waves done READING prev tile
    __builtin_amdgcn_sched_barrier(0);
    write_lds();                                   // implicit vmcnt wait on kreg/vreg here
    if (nxt < 16) issue(nxt);                      // issue-early: hides under compute below
    asm volatile("s_waitcnt lgkmcnt(0)" ::: "memory");   // my ds_writes visible
    __builtin_amdgcn_s_barrier();                  // everyone's writes visible
    __builtin_amdgcn_sched_barrier(0);
    compute(cur);
    cur = nxt;
  }

  // ---- epilogue -------------------------------------------------------------------------
  rs += __shfl_xor(rs, 16, 64);
  rs += __shfl_xor(rs, 32, 64);
  const float rinv = 1.0f / rs;
  #pragma unroll
  for (int ct=0;ct<4;++ct){
    short4v o4;
    #pragma unroll
    for (int r=0;r<4;++r) o4[r] = (short)f2b(acc[ct][r] * rinv);
    *(short4v*)&Ot[((size_t)b*S + qg)*1024 + h*64 + ct*16 + quad*4] = o4;
  }
}

extern "C" void kernel_launch(void* const* d_in, const int* in_sizes, int n_in,
                              void* d_out, int out_size, void* d_ws, size_t ws_size,
                              hipStream_t stream)
{
  const float* q   = (const float*)d_in[0];
  const float* k   = (const float*)d_in[1];
  const float* v   = (const float*)d_in[2];
  const float* qkm = (const float*)d_in[3];
  const float* km  = (const float*)d_in[4];
  const float* Wq  = (const float*)d_in[5];
  const float* bq  = (const float*)d_in[6];
  const float* Wk  = (const float*)d_in[7];
  const float* bk  = (const float*)d_in[8];
  const float* Wv  = (const float*)d_in[9];
  const float* bv  = (const float*)d_in[10];
  const float* Wo  = (const float*)d_in[11];
  const float* bo  = (const float*)d_in[12];
  float* out = (float*)d_out;

  const size_t nAct = (size_t)2*2048*1024;   // 4M elems per activation buffer
  const int   nW   = 1024*1024;

  u16* A0 = (u16*)d_ws;          // qT, later attn output Ot
  u16* A1 = A0 + nAct;           // kT
  u16* A2 = A1 + nAct;           // vT
  u16* A3 = A2 + nAct;           // Qb
  u16* A4 = A3 + nAct;           // Kb
  u16* A5 = A4 + nAct;           // Vb
  u16* W16 = A5 + nAct;          // Wq16|Wk16|Wv16|Wo16
  char* classes = (char*)(W16 + (size_t)4*nW);   // 2 KB
  u16* Wo16 = W16 + (size_t)3*nW;

  dim3 blk(256);
  prep      <<<dim3(7168), blk, 0, stream>>>(q, k, v, qkm, km, Wq, Wk, Wv, Wo,
                                             W16, classes, A0, A1, A2);
  proj      <<<dim3(768),  blk, 0, stream>>>(A0, A1, A2, W16, bq, bk, bv, A3, A4, A5);
  attn      <<<dim3(1024), blk, 0, stream>>>(A3, A4, A5, qkm, km, classes, A0);
  gemm_out64<<<dim3(16,16,2), blk, 0, stream>>>(Wo16, A0, bo, out);
}